// Round 5
// baseline (151.078 us; speedup 1.0000x reference)
//
#include <hip/hip_runtime.h>
#include <math.h>

// Problem constants
#define BN   4
#define CN   256
#define HN   128
#define WN   128
#define COMP 64
#define KK   25      // K*K taps
#define HO   64
#define WO   64

// ---------------- workspace layout (float offsets) ----------------
// w1B  : 16 kidx x 2 nt x 64 lane x 8 bf16  = 16384 u16 = 8192 float slots
// w2A  : 9 t x 4 kidx x 64 lane x 8 bf16    = 18432 u16 = 9216 float slots
// (mask region from R4 retained but unused)
// comp : BN*HN*WN*COMP bf16                  = 4194304 u16 = 2097152 slots
#define W1B_OFF  0
#define W2A_OFF  8192
#define MASK_OFF 17408
#define COMP_OFF 427008
#define WS_NEED  ((size_t)(COMP_OFF + (size_t)BN * HN * WN * COMP / 2) * 4)

typedef short v8s  __attribute__((ext_vector_type(8)));
typedef float v16f __attribute__((ext_vector_type(16)));

__device__ inline ushort f2bf(float f) {       // fp32 -> bf16 bits, RNE
  unsigned u = __float_as_uint(f);
  return (ushort)((u + 0x7fffu + ((u >> 16) & 1u)) >> 16);
}

// ---------------------------------------------------------------------------
// compose_frags: 68 blocks x 64 thr. (R4-proven)
//  bid<32 : w1B B-fragments for compress GEMM.
//  bid>=32: w2A A-fragments for mask conv.
// ---------------------------------------------------------------------------
__global__ __launch_bounds__(64) void compose_frags(
    const float* __restrict__ w1, const float* __restrict__ w2,
    float* __restrict__ ws) {
  const int bid = blockIdx.x;
  const int lane = threadIdx.x;
  const int k0 = (lane >> 5) * 8;
  ushort pk[8];
  ushort* dst;
  if (bid < 32) {
    const int kidx = bid >> 1, nt = bid & 1;
    const int ch = nt * 32 + (lane & 31);
    const int c0 = kidx * 16 + k0;
#pragma unroll
    for (int j = 0; j < 8; ++j) pk[j] = f2bf(w1[(size_t)ch * CN + c0 + j]);
    dst = (ushort*)(ws + W1B_OFF) + ((size_t)((kidx * 2 + nt) * 64 + lane)) * 8;
  } else {
    const int g = bid - 32;
    const int t = g >> 2, kidx = g & 3;
    const int m = lane & 31;
    const int kk0 = kidx * 16 + k0;
#pragma unroll
    for (int j = 0; j < 8; ++j) {
      float v = (m < KK) ? w2[((size_t)(m * COMP + kk0 + j)) * 9 + t] : 0.f;
      pk[j] = f2bf(v);
    }
    dst = (ushort*)(ws + W2A_OFF) + ((size_t)((t * 4 + kidx) * 64 + lane)) * 8;
  }
  *(ushort4*)(dst)     = make_ushort4(pk[0], pk[1], pk[2], pk[3]);
  *(ushort4*)(dst + 4) = make_ushort4(pk[4], pk[5], pk[6], pk[7]);
}

// ---------------------------------------------------------------------------
// compress: comp[b][h][px][ch] = bf16( w1 . x + b1 ). (R4-proven, unchanged)
// grid (HN, BN) x 256 thr. Pure MFMA GEMM, no LDS, no barriers.
// ---------------------------------------------------------------------------
__global__ __launch_bounds__(256, 4) void compress_kernel(
    const float* __restrict__ x, const float* __restrict__ b1,
    float* __restrict__ ws) {
  const int h = blockIdx.x, b = blockIdx.y;
  const int tid = threadIdx.x;
  const int lane = tid & 63, w = tid >> 6;
  const int nn = lane & 31, kh = lane >> 5;
  const int px = w * 32 + nn;
  const ushort* w1B = (const ushort*)(ws + W1B_OFF);
  v16f acc[2] = {{}, {}};
#pragma unroll 2
  for (int kidx = 0; kidx < 16; ++kidx) {
    const float* xc = x + (((size_t)(b * CN + kidx * 16 + kh * 8)) * HN + h) * WN + px;
    float av[8];
#pragma unroll
    for (int j = 0; j < 8; ++j) av[j] = xc[(size_t)j * (HN * WN)];
    v8s af;
#pragma unroll
    for (int j = 0; j < 8; ++j) af[j] = (short)f2bf(av[j]);
    v8s bf0 = *(const v8s*)(w1B + ((size_t)((kidx * 2 + 0) * 64 + lane)) * 8);
    v8s bf1 = *(const v8s*)(w1B + ((size_t)((kidx * 2 + 1) * 64 + lane)) * 8);
    acc[0] = __builtin_amdgcn_mfma_f32_32x32x16_bf16(af, bf0, acc[0], 0, 0, 0);
    acc[1] = __builtin_amdgcn_mfma_f32_32x32x16_bf16(af, bf1, acc[1], 0, 0, 0);
  }
  ushort* comp = (ushort*)(ws + COMP_OFF);
  const size_t rowbase = (size_t)(b * HN + h) * WN;
#pragma unroll
  for (int nt = 0; nt < 2; ++nt) {
    const float bias = b1[nt * 32 + nn];
#pragma unroll
    for (int rg = 0; rg < 16; ++rg) {
      const int pr = w * 32 + (rg & 3) + 8 * (rg >> 2) + 4 * kh;
      comp[(rowbase + pr) * COMP + nt * 32 + nn] = f2bf(acc[nt][rg] + bias);
    }
  }
}

// ---------------------------------------------------------------------------
// mask_gather: grid (HO, BN, 2 ch-halves) x 512 thr (8 waves).
// Each block computes the FULL 25x64 mask for its (ho,b) row (duplicated
// across the two halves -- cheap) and gathers its 128-channel half.
//   stage: comp rows 2ho-1..2ho+1 -> XOR-swizzled LDS bf16 (R4-proven).
//   MFMA (waves 0-3 only): nt=w&1 px-tile, kh2=w>>1 K-half; 18 MFMA each
//     (exact R4 mask_softmax code).
//   All 8 waves issue their gather x prefetch right after the stage barrier
//     (waves 4-7 immediately; waves 0-3 after MFMA) -> loads fly during
//     the reduce/softmax phase.
//   Reduce 2-way over kh2 + 64-thread softmax -> sml (R4-proven).
//   Gather: 8 waves x 16 ch, exact R1-proven body. c_base = h*128 + wv*16.
// LDS: stage 49152 B (red 6400 B aliases after barrier) + sml 6400 = 55552 B
//   -> 2 blocks/CU (LDS-capped), 16 waves/CU during gather phase.
// launch_bounds(512,4) -> VGPR cap 128 (spill tripwire: WRITE_SIZE >> 16 MB).
// ---------------------------------------------------------------------------
#define MG_SML 49152
#define MG_LDS (49152 + 6400)
__global__ __launch_bounds__(512, 4) void mask_gather(
    const float* __restrict__ ws, const float* __restrict__ b2,
    const float* __restrict__ x, float* __restrict__ out) {
  const int ho = blockIdx.x, b = blockIdx.y, h = blockIdx.z;
  const int tid = threadIdx.x;
  const int lane = tid & 63, wv = tid >> 6;    // wv 0..7

  __shared__ __attribute__((aligned(16))) char smem[MG_LDS];
  float* red = (float*)smem;                   // aliases stage after barrier
  float* sml = (float*)(smem + MG_SML);
  const ushort* comp = (const ushort*)(ws + COMP_OFF);
  const float* __restrict__ xb = x + (size_t)(b * CN) * (HN * WN);

  // ---- stage 3 comp rows (3072 v8s over 512 thr = 6 iters) ----
#pragma unroll
  for (int i = 0; i < 6; ++i) {
    const int flat = i * 512 + tid;            // 0..3071
    const int r = flat >> 10;                  // 0..2
    const int px = (flat >> 3) & 127;
    const int cg = flat & 7;
    const int rr = 2 * ho + r - 1;
    v8s v = {};
    if (rr >= 0)
      v = *(const v8s*)(comp + ((size_t)(b * HN + rr) * WN + px) * COMP + cg * 8);
    const int boff = (((r * 128 + px) * 64 + cg * 8) * 2) ^ (((px >> 1) & 7) << 4);
    *(v8s*)(smem + boff) = v;
  }
  __syncthreads();

  // ---- MFMA (waves 0-3), exact R4 mask_softmax body ----
  const int nt = wv & 1, kh2 = wv >> 1;        // kh2 >= 2 for wv >= 4
  const int nn = lane & 31;
  v16f acc = {};
  if (wv < 4) {
    const ushort* w2A = (const ushort*)(ws + W2A_OFF);
    const v8s zero8 = {};
#pragma unroll
    for (int t = 0; t < 9; ++t) {
      const int dr = t / 3, dc = t % 3;
#pragma unroll
      for (int ki = 0; ki < 2; ++ki) {
        const int kidx = kh2 * 2 + ki;
        const v8s af = *(const v8s*)(w2A + ((size_t)((t * 4 + kidx) * 64 + lane)) * 8);
        const int q = 2 * (nt * 32 + nn) + dc - 1;
        const bool bad = q < 0;                // only nt==0, nn==0, dc==0
        const int qc = bad ? 0 : q;
        const int boff = (((dr * 128 + qc) * 64 + kidx * 16 + (lane >> 5) * 8) * 2)
                         ^ (((qc >> 1) & 7) << 4);
        v8s bf = *(const v8s*)(smem + boff);
        if (dc == 0 && bad) bf = zero8;
        acc = __builtin_amdgcn_mfma_f32_32x32x16_bf16(af, bf, acc, 0, 0, 0);
      }
    }
  }

  // ---- gather prefetch (all waves; flies during reduce+softmax) ----
  const int wo = lane;
  const int c_base = __builtin_amdgcn_readfirstlane(h * 128 + wv * 16);
  const int col = 2 * wo;
  float2 g[2][5];
  auto load_g = [&](int ci, float2* dst) {
    const float* xc = xb + (size_t)(c_base + ci) * (HN * WN);
#pragma unroll
    for (int i = 0; i < 5; ++i) {
      int r = 2 * ho - 2 + i;
      dst[i] = (r >= 0 && r < HN) ? *(const float2*)(xc + r * WN + col)
                                  : make_float2(0.f, 0.f);
    }
  };
  load_g(0, g[0]);
  load_g(1, g[1]);

  __syncthreads();                             // stage reads done; red aliases

  // ---- reduce over kh2 (waves 0-3 only), R4-proven ----
  if (kh2 == 1) {
#pragma unroll
    for (int rg = 0; rg < 16; ++rg) {
      const int m = (rg & 3) + 8 * (rg >> 2) + 4 * (lane >> 5);
      if (m < KK) red[(nt * KK + m) * 32 + nn] = acc[rg];
    }
  }
  __syncthreads();
  if (kh2 == 0) {
#pragma unroll
    for (int rg = 0; rg < 16; ++rg) {
      const int m = (rg & 3) + 8 * (rg >> 2) + 4 * (lane >> 5);
      if (m < KK) red[(nt * KK + m) * 32 + nn] += acc[rg];
    }
  }
  __syncthreads();

  // ---- softmax (64 threads, one per wo) -> sml ----
  if (tid < 64) {
    const int tnt = tid >> 5, tc = tid & 31;
    float logit[KK];
    float mx = -1e30f;
#pragma unroll
    for (int m = 0; m < KK; ++m) {
      float l = b2[m] + red[(tnt * KK + m) * 32 + tc];
      logit[m] = l;
      mx = fmaxf(mx, l);
    }
    float ssum = 0.f;
#pragma unroll
    for (int m = 0; m < KK; ++m) {
      float e = __expf(logit[m] - mx);
      logit[m] = e;
      ssum += e;
    }
    const float inv = 1.f / ssum;
#pragma unroll
    for (int m = 0; m < KK; ++m) sml[m * 64 + tid] = logit[m] * inv;
  }
  __syncthreads();

  // ---- gather (all 8 waves, 16 ch each), exact R1-proven body ----
  float smr[KK];
#pragma unroll
  for (int m = 0; m < KK; ++m) smr[m] = sml[m * 64 + wo];

  const float wok = (wo > 0) ? 1.f : 0.f;
  const float w63 = (wo < 63) ? 1.f : 0.f;
  for (int ci = 0; ci < 16; ++ci) {
    float2 v[5];
#pragma unroll
    for (int i = 0; i < 5; ++i) v[i] = g[ci & 1][i];
    if (ci + 2 < 16) load_g(ci + 2, g[ci & 1]);

    float acc2 = 0.f;
#pragma unroll
    for (int i = 0; i < 5; ++i) {
      float lx = wok * __shfl_up(v[i].x, 1, 64);    // col 2wo-2
      float ly = wok * __shfl_up(v[i].y, 1, 64);    // col 2wo-1
      float rx = w63 * __shfl_down(v[i].x, 1, 64);  // col 2wo+2
      acc2 += lx * smr[i * 5 + 0] + ly * smr[i * 5 + 1]
            + v[i].x * smr[i * 5 + 2] + v[i].y * smr[i * 5 + 3]
            + rx * smr[i * 5 + 4];
    }
    out[(((size_t)(b * CN + c_base + ci)) * HO + ho) * WO + wo] = acc2;
  }
}

// ============================ FALLBACK PATH ================================
// Round-2 proven kernels (used only if ws_size < WS_NEED).
#define FB_WSTRIDE 240
#define FB_TB_OFF  (256 * FB_WSTRIDE)

__global__ __launch_bounds__(256) void compose_w_fb(
    const float* __restrict__ w1, const float* __restrict__ b1,
    const float* __restrict__ w2, float* __restrict__ ws) {
  int mt = blockIdx.x, c = threadIdx.x;
  float acc = 0.f;
#pragma unroll 8
  for (int k = 0; k < COMP; ++k)
    acc += w2[(size_t)(mt / 9 * COMP + k) * 9 + (mt % 9)] * w1[k * CN + c];
  ws[c * FB_WSTRIDE + mt] = acc;
  if (mt < FB_WSTRIDE - 225) ws[c * FB_WSTRIDE + 225 + mt] = 0.f;
  if (c == 0) {
    float tbv = 0.f;
    for (int k = 0; k < COMP; ++k)
      tbv += w2[(size_t)(mt / 9 * COMP + k) * 9 + (mt % 9)] * b1[k];
    ws[FB_TB_OFF + mt] = tbv;
  }
}

__global__ __launch_bounds__(1024, 4) void fused_fb(
    const float* __restrict__ x, const float* __restrict__ b2,
    const float* __restrict__ ws, float* __restrict__ out) {
  const int ho = blockIdx.x, b = blockIdx.y, tid = threadIdx.x;
  const int wo = tid & 63, wv = tid >> 6;
  const int c_base = __builtin_amdgcn_readfirstlane(wv * 16);
  const float* __restrict__ w2c = ws;
  const float* __restrict__ tb  = ws + FB_TB_OFF;
  __shared__ float red[8 * KK * 64];
  __shared__ float sm[KK * 64];
  const float* __restrict__ xb = x + (size_t)(b * CN) * (HN * WN);
  const int col = 2 * wo;
  float acc[KK];
#pragma unroll
  for (int m = 0; m < KK; ++m) acc[m] = 0.f;
  float2 xbuf[2][3];
  auto load_ch = [&](int ci, float2* dst) {
    const float* xc = xb + (size_t)(c_base + ci) * (HN * WN);
    dst[0] = (ho > 0) ? *(const float2*)(xc + (2 * ho - 1) * WN + col)
                      : make_float2(0.f, 0.f);
    dst[1] = *(const float2*)(xc + (2 * ho) * WN + col);
    dst[2] = *(const float2*)(xc + (2 * ho + 1) * WN + col);
  };
  load_ch(0, xbuf[0]);
  load_ch(1, xbuf[1]);
  const float wok = (wo > 0) ? 1.f : 0.f;
  for (int ci = 0; ci < 16; ++ci) {
    float2 r0 = xbuf[ci & 1][0], r1 = xbuf[ci & 1][1], r2 = xbuf[ci & 1][2];
    if (ci + 2 < 16) load_ch(ci + 2, xbuf[ci & 1]);
    float xv[9];
    xv[0] = wok * __shfl_up(r0.y, 1, 64); xv[1] = r0.x; xv[2] = r0.y;
    xv[3] = wok * __shfl_up(r1.y, 1, 64); xv[4] = r1.x; xv[5] = r1.y;
    xv[6] = wok * __shfl_up(r2.y, 1, 64); xv[7] = r2.x; xv[8] = r2.y;
    const float* __restrict__ wrow = w2c + (size_t)(c_base + ci) * FB_WSTRIDE;
#pragma unroll
    for (int m = 0; m < KK; ++m) {
      float a = acc[m];
#pragma unroll
      for (int t = 0; t < 9; ++t) a += wrow[m * 9 + t] * xv[t];
      acc[m] = a;
    }
  }
  float2 g[2][5];
  auto load_g = [&](int ci, float2* dst) {
    const float* xc = xb + (size_t)(c_base + ci) * (HN * WN);
#pragma unroll
    for (int i = 0; i < 5; ++i) {
      int r = 2 * ho - 2 + i;
      dst[i] = (r >= 0 && r < HN) ? *(const float2*)(xc + r * WN + col)
                                  : make_float2(0.f, 0.f);
    }
  };
  load_g(0, g[0]);
  load_g(1, g[1]);
  if (wv >= 8) {
#pragma unroll
    for (int m = 0; m < KK; ++m) red[((wv - 8) * KK + m) * 64 + wo] = acc[m];
  }
  __syncthreads();
  if (wv < 8) {
#pragma unroll
    for (int m = 0; m < KK; ++m) red[(wv * KK + m) * 64 + wo] += acc[m];
  }
  __syncthreads();
  if (wv < 4) {
#pragma unroll
    for (int m = 0; m < KK; ++m)
      red[(wv * KK + m) * 64 + wo] += red[((wv + 4) * KK + m) * 64 + wo];
  }
  __syncthreads();
  if (wv < 2) {
#pragma unroll
    for (int m = 0; m < KK; ++m)
      red[(wv * KK + m) * 64 + wo] += red[((wv + 2) * KK + m) * 64 + wo];
  }
  __syncthreads();
  if (tid < 64) {
    const float vr0 = (ho > 0) ? 1.f : 0.f;
    const float vq0 = (wo > 0) ? 1.f : 0.f;
    float logit[KK];
    float mx = -1e30f;
#pragma unroll
    for (int m = 0; m < KK; ++m) {
      const float* t9 = tb + m * 9;
      float l = b2[m]
              + vr0 * (vq0 * t9[0] + t9[1] + t9[2])
              +       (vq0 * t9[3] + t9[4] + t9[5])
              +       (vq0 * t9[6] + t9[7] + t9[8]);
      l += red[(0 * KK + m) * 64 + wo] + red[(1 * KK + m) * 64 + wo];
      logit[m] = l;
      mx = fmaxf(mx, l);
    }
    float s = 0.f;
#pragma unroll
    for (int m = 0; m < KK; ++m) {
      float e = __expf(logit[m] - mx);
      logit[m] = e;
      s += e;
    }
    float inv = 1.f / s;
#pragma unroll
    for (int m = 0; m < KK; ++m) sm[m * 64 + wo] = logit[m] * inv;
  }
  __syncthreads();
  float smr[KK];
#pragma unroll
  for (int m = 0; m < KK; ++m) smr[m] = sm[m * 64 + wo];
  const float w63 = (wo < 63) ? 1.f : 0.f;
  for (int ci = 0; ci < 16; ++ci) {
    float2 v[5];
#pragma unroll
    for (int i = 0; i < 5; ++i) v[i] = g[ci & 1][i];
    if (ci + 2 < 16) load_g(ci + 2, g[ci & 1]);
    float acc2 = 0.f;
#pragma unroll
    for (int i = 0; i < 5; ++i) {
      float lx = wok * __shfl_up(v[i].x, 1, 64);
      float ly = wok * __shfl_up(v[i].y, 1, 64);
      float rx = w63 * __shfl_down(v[i].x, 1, 64);
      acc2 += lx * smr[i * 5 + 0] + ly * smr[i * 5 + 1]
            + v[i].x * smr[i * 5 + 2] + v[i].y * smr[i * 5 + 3]
            + rx * smr[i * 5 + 4];
    }
    out[(((size_t)(b * CN + c_base + ci)) * HO + ho) * WO + wo] = acc2;
  }
}

// ---------------------------------------------------------------------------
extern "C" void kernel_launch(void* const* d_in, const int* in_sizes, int n_in,
                              void* d_out, int out_size, void* d_ws, size_t ws_size,
                              hipStream_t stream) {
  const float* x  = (const float*)d_in[0];
  const float* w1 = (const float*)d_in[1];
  const float* b1 = (const float*)d_in[2];
  const float* w2 = (const float*)d_in[3];
  const float* b2 = (const float*)d_in[4];
  float* out = (float*)d_out;
  float* ws  = (float*)d_ws;

  if (ws_size >= WS_NEED) {
    hipLaunchKernelGGL(compose_frags, dim3(68), dim3(64), 0, stream,
                       w1, w2, ws);
    hipLaunchKernelGGL(compress_kernel, dim3(HN, BN), dim3(256), 0, stream,
                       x, b1, ws);
    hipLaunchKernelGGL(mask_gather, dim3(HO, BN, 2), dim3(512), 0, stream,
                       ws, b2, x, out);
  } else {
    hipLaunchKernelGGL(compose_w_fb, dim3(225), dim3(256), 0, stream,
                       w1, b1, w2, ws);
    hipLaunchKernelGGL(fused_fb, dim3(HO, BN), dim3(1024), 0, stream,
                       x, b2, ws, out);
  }
}

// Round 6
// 139.186 us; speedup vs baseline: 1.0854x; 1.0854x over previous
//
#include <hip/hip_runtime.h>
#include <math.h>

// Problem constants
#define BN   4
#define CN   256
#define HN   128
#define WN   128
#define COMP 64
#define KK   25      // K*K taps
#define HO   64
#define WO   64

// ---------------- workspace layout (float offsets) ----------------
// w1B  : 16 kidx x 2 nt x 64 lane x 8 bf16  = 16384 u16 = 8192 float slots
// w2A  : 9 t x 4 kidx x 64 lane x 8 bf16    = 18432 u16 = 9216 float slots
// mask : BN*HO*KK*64 fp32                    = 409600 floats
// comp : BN*HN*WN*COMP bf16                  = 4194304 u16 = 2097152 slots
#define W1B_OFF  0
#define W2A_OFF  8192
#define MASK_OFF 17408
#define COMP_OFF 427008
#define WS_NEED  ((size_t)(COMP_OFF + (size_t)BN * HN * WN * COMP / 2) * 4)

typedef short v8s  __attribute__((ext_vector_type(8)));
typedef float v16f __attribute__((ext_vector_type(16)));

__device__ inline ushort f2bf(float f) {       // fp32 -> bf16 bits, RNE
  unsigned u = __float_as_uint(f);
  return (ushort)((u + 0x7fffu + ((u >> 16) & 1u)) >> 16);
}

// ---------------------------------------------------------------------------
// compose_frags: 68 blocks x 64 thr. (R4-proven, unchanged)
//  bid<32 : w1B B-fragments for compress GEMM.
//  bid>=32: w2A A-fragments for mask conv.
// ---------------------------------------------------------------------------
__global__ __launch_bounds__(64) void compose_frags(
    const float* __restrict__ w1, const float* __restrict__ w2,
    float* __restrict__ ws) {
  const int bid = blockIdx.x;
  const int lane = threadIdx.x;
  const int k0 = (lane >> 5) * 8;
  ushort pk[8];
  ushort* dst;
  if (bid < 32) {
    const int kidx = bid >> 1, nt = bid & 1;
    const int ch = nt * 32 + (lane & 31);
    const int c0 = kidx * 16 + k0;
#pragma unroll
    for (int j = 0; j < 8; ++j) pk[j] = f2bf(w1[(size_t)ch * CN + c0 + j]);
    dst = (ushort*)(ws + W1B_OFF) + ((size_t)((kidx * 2 + nt) * 64 + lane)) * 8;
  } else {
    const int g = bid - 32;
    const int t = g >> 2, kidx = g & 3;
    const int m = lane & 31;
    const int kk0 = kidx * 16 + k0;
#pragma unroll
    for (int j = 0; j < 8; ++j) {
      float v = (m < KK) ? w2[((size_t)(m * COMP + kk0 + j)) * 9 + t] : 0.f;
      pk[j] = f2bf(v);
    }
    dst = (ushort*)(ws + W2A_OFF) + ((size_t)((t * 4 + kidx) * 64 + lane)) * 8;
  }
  *(ushort4*)(dst)     = make_ushort4(pk[0], pk[1], pk[2], pk[3]);
  *(ushort4*)(dst + 4) = make_ushort4(pk[4], pk[5], pk[6], pk[7]);
}

// ---------------------------------------------------------------------------
// compress: comp[b][h][px][ch] = bf16( w1 . x + b1 ).
// grid (HN, BN) x 512 thr (8 waves -> 4 waves/SIMD, 2x R4's TLP).
// Wave w: px-tile tw = w&3, ch-half nt = w>>2; 16 MFMA chain, no LDS,
// no barriers. Same output mapping as the R4-proven 4-wave version
// (R4 wave did both nt; here one wave per (tw,nt)).
// D layout: col(ch)=lane&31, row(px)=(reg&3)+8*(reg>>2)+4*(lane>>5).
// ---------------------------------------------------------------------------
__global__ __launch_bounds__(512, 4) void compress_kernel(
    const float* __restrict__ x, const float* __restrict__ b1,
    float* __restrict__ ws) {
  const int h = blockIdx.x, b = blockIdx.y;
  const int tid = threadIdx.x;
  const int lane = tid & 63, w = tid >> 6;     // w 0..7
  const int tw = w & 3, nt = w >> 2;           // px-tile, ch-half
  const int nn = lane & 31, kh = lane >> 5;
  const int px = tw * 32 + nn;
  const ushort* w1B = (const ushort*)(ws + W1B_OFF);
  v16f acc = {};
#pragma unroll 2
  for (int kidx = 0; kidx < 16; ++kidx) {
    const float* xc = x + (((size_t)(b * CN + kidx * 16 + kh * 8)) * HN + h) * WN + px;
    float av[8];
#pragma unroll
    for (int j = 0; j < 8; ++j) av[j] = xc[(size_t)j * (HN * WN)];
    v8s af;
#pragma unroll
    for (int j = 0; j < 8; ++j) af[j] = (short)f2bf(av[j]);
    v8s bf = *(const v8s*)(w1B + ((size_t)((kidx * 2 + nt) * 64 + lane)) * 8);
    acc = __builtin_amdgcn_mfma_f32_32x32x16_bf16(af, bf, acc, 0, 0, 0);
  }
  ushort* comp = (ushort*)(ws + COMP_OFF);
  const size_t rowbase = (size_t)(b * HN + h) * WN;
  const float bias = b1[nt * 32 + nn];
#pragma unroll
  for (int rg = 0; rg < 16; ++rg) {
    const int pr = tw * 32 + (rg & 3) + 8 * (rg >> 2) + 4 * kh;
    comp[(rowbase + pr) * COMP + nt * 32 + nn] = f2bf(acc[rg] + bias);
  }
}

// ---------------------------------------------------------------------------
// mask_softmax: grid (HO, BN) x 256 thr (4 waves). (R4-proven, unchanged)
// ---------------------------------------------------------------------------
#define MS_LDS 49152
__global__ __launch_bounds__(256, 4) void mask_softmax(
    const float* __restrict__ b2, float* __restrict__ ws) {
  const int ho = blockIdx.x, b = blockIdx.y;
  const int tid = threadIdx.x;
  const int lane = tid & 63, w = tid >> 6;
  __shared__ __attribute__((aligned(16))) char smem[MS_LDS];
  float* red = (float*)smem;                   // alias after barrier
  const ushort* comp = (const ushort*)(ws + COMP_OFF);

  // ---- stage 3 rows (3*128*8 = 3072 v8s) ----
#pragma unroll
  for (int i = 0; i < 12; ++i) {
    const int flat = i * 256 + tid;            // 0..3071
    const int r = flat >> 10;                  // 0..2
    const int px = (flat >> 3) & 127;
    const int cg = flat & 7;
    const int rr = 2 * ho + r - 1;
    v8s v = {};
    if (rr >= 0)
      v = *(const v8s*)(comp + ((size_t)(b * HN + rr) * WN + px) * COMP + cg * 8);
    const int boff = (((r * 128 + px) * 64 + cg * 8) * 2) ^ (((px >> 1) & 7) << 4);
    *(v8s*)(smem + boff) = v;
  }
  __syncthreads();

  // ---- MFMA ----
  const int nt = w & 1, kh2 = w >> 1;
  const int nn = lane & 31;
  const ushort* w2A = (const ushort*)(ws + W2A_OFF);
  const v8s zero8 = {};
  v16f acc = {};
#pragma unroll
  for (int t = 0; t < 9; ++t) {
    const int dr = t / 3, dc = t % 3;
#pragma unroll
    for (int ki = 0; ki < 2; ++ki) {
      const int kidx = kh2 * 2 + ki;
      const v8s af = *(const v8s*)(w2A + ((size_t)((t * 4 + kidx) * 64 + lane)) * 8);
      const int q = 2 * (nt * 32 + nn) + dc - 1;
      const bool bad = q < 0;                  // only nt==0, nn==0, dc==0
      const int qc = bad ? 0 : q;
      const int boff = (((dr * 128 + qc) * 64 + kidx * 16 + (lane >> 5) * 8) * 2)
                       ^ (((qc >> 1) & 7) << 4);
      v8s bf = *(const v8s*)(smem + boff);
      if (dc == 0 && bad) bf = zero8;
      acc = __builtin_amdgcn_mfma_f32_32x32x16_bf16(af, bf, acc, 0, 0, 0);
    }
  }
  __syncthreads();                             // stage reads done; red aliases

  // ---- reduce over kh2 ----
  if (kh2 == 1) {
#pragma unroll
    for (int rg = 0; rg < 16; ++rg) {
      const int m = (rg & 3) + 8 * (rg >> 2) + 4 * (lane >> 5);
      if (m < KK) red[(nt * KK + m) * 32 + nn] = acc[rg];
    }
  }
  __syncthreads();
  if (kh2 == 0) {
#pragma unroll
    for (int rg = 0; rg < 16; ++rg) {
      const int m = (rg & 3) + 8 * (rg >> 2) + 4 * (lane >> 5);
      if (m < KK) red[(nt * KK + m) * 32 + nn] += acc[rg];
    }
  }
  __syncthreads();

  // ---- softmax (64 threads, one per wo) ----
  if (tid < 64) {
    const int wo = tid;
    const int tnt = wo >> 5, tc = wo & 31;
    float logit[KK];
    float mx = -1e30f;
#pragma unroll
    for (int m = 0; m < KK; ++m) {
      float l = b2[m] + red[(tnt * KK + m) * 32 + tc];
      logit[m] = l;
      mx = fmaxf(mx, l);
    }
    float ssum = 0.f;
#pragma unroll
    for (int m = 0; m < KK; ++m) {
      float e = __expf(logit[m] - mx);
      logit[m] = e;
      ssum += e;
    }
    const float inv = 1.f / ssum;
    float* mdst = ws + MASK_OFF + (size_t)(b * HO + ho) * KK * 64;
#pragma unroll
    for (int m = 0; m < KK; ++m) mdst[m * 64 + wo] = logit[m] * inv;
  }
}

// ---------------------------------------------------------------------------
// gather: 1024 blocks x 256 thr (4 waves). R4-proven body; prefetch ring
// deepened 2 -> 4 (L3 latency ~500+ cyc vs ~130 cyc compute per ci) with
// explicit unroll so g[ci&3] stays statically indexed (no scratch).
// ---------------------------------------------------------------------------
__global__ __launch_bounds__(256, 4) void gather_kernel(
    const float* __restrict__ ws, const float* __restrict__ x,
    float* __restrict__ out) {
  const int bid0 = blockIdx.x;
  const int bid = (bid0 & 7) * 128 + (bid0 >> 3);   // bijective (1024 = 8*128)
  const int ho = bid & 63;
  const int cq = (bid >> 6) & 3;
  const int b = bid >> 8;
  const int tid = threadIdx.x;
  const int lane = tid & 63, wv = tid >> 6;

  __shared__ float sml[KK * 64];               // 6400 B

  const float* __restrict__ xb = x + (size_t)(b * CN) * (HN * WN);
  const int wo = lane;
  const int c_base = __builtin_amdgcn_readfirstlane(cq * 64 + wv * 16);
  const int col = 2 * wo;
  float2 g[4][5];
  auto load_g = [&](int ci, float2* dst) {
    const float* xc = xb + (size_t)(c_base + ci) * (HN * WN);
#pragma unroll
    for (int i = 0; i < 5; ++i) {
      int r = 2 * ho - 2 + i;
      dst[i] = (r >= 0 && r < HN) ? *(const float2*)(xc + r * WN + col)
                                  : make_float2(0.f, 0.f);
    }
  };
  load_g(0, g[0]);
  load_g(1, g[1]);
  load_g(2, g[2]);
  load_g(3, g[3]);

  const float* msrc = ws + MASK_OFF + (size_t)(b * HO + ho) * KK * 64;
  for (int i = tid; i < KK * 64; i += 256) sml[i] = msrc[i];
  __syncthreads();

  float smr[KK];
#pragma unroll
  for (int m = 0; m < KK; ++m) smr[m] = sml[m * 64 + wo];

  const float wok = (wo > 0) ? 1.f : 0.f;
  const float w63 = (wo < 63) ? 1.f : 0.f;
#pragma unroll
  for (int ci = 0; ci < 16; ++ci) {
    float2 v[5];
#pragma unroll
    for (int i = 0; i < 5; ++i) v[i] = g[ci & 3][i];
    if (ci + 4 < 16) load_g(ci + 4, g[ci & 3]);

    float acc2 = 0.f;
#pragma unroll
    for (int i = 0; i < 5; ++i) {
      float lx = wok * __shfl_up(v[i].x, 1, 64);    // col 2wo-2
      float ly = wok * __shfl_up(v[i].y, 1, 64);    // col 2wo-1
      float rx = w63 * __shfl_down(v[i].x, 1, 64);  // col 2wo+2
      acc2 += lx * smr[i * 5 + 0] + ly * smr[i * 5 + 1]
            + v[i].x * smr[i * 5 + 2] + v[i].y * smr[i * 5 + 3]
            + rx * smr[i * 5 + 4];
    }
    out[(((size_t)(b * CN + c_base + ci)) * HO + ho) * WO + wo] = acc2;
  }
}

// ============================ FALLBACK PATH ================================
// Round-2 proven kernels (used only if ws_size < WS_NEED).
#define FB_WSTRIDE 240
#define FB_TB_OFF  (256 * FB_WSTRIDE)

__global__ __launch_bounds__(256) void compose_w_fb(
    const float* __restrict__ w1, const float* __restrict__ b1,
    const float* __restrict__ w2, float* __restrict__ ws) {
  int mt = blockIdx.x, c = threadIdx.x;
  float acc = 0.f;
#pragma unroll 8
  for (int k = 0; k < COMP; ++k)
    acc += w2[(size_t)(mt / 9 * COMP + k) * 9 + (mt % 9)] * w1[k * CN + c];
  ws[c * FB_WSTRIDE + mt] = acc;
  if (mt < FB_WSTRIDE - 225) ws[c * FB_WSTRIDE + 225 + mt] = 0.f;
  if (c == 0) {
    float tbv = 0.f;
    for (int k = 0; k < COMP; ++k)
      tbv += w2[(size_t)(mt / 9 * COMP + k) * 9 + (mt % 9)] * b1[k];
    ws[FB_TB_OFF + mt] = tbv;
  }
}

__global__ __launch_bounds__(1024, 4) void fused_fb(
    const float* __restrict__ x, const float* __restrict__ b2,
    const float* __restrict__ ws, float* __restrict__ out) {
  const int ho = blockIdx.x, b = blockIdx.y, tid = threadIdx.x;
  const int wo = tid & 63, wv = tid >> 6;
  const int c_base = __builtin_amdgcn_readfirstlane(wv * 16);
  const float* __restrict__ w2c = ws;
  const float* __restrict__ tb  = ws + FB_TB_OFF;
  __shared__ float red[8 * KK * 64];
  __shared__ float sm[KK * 64];
  const float* __restrict__ xb = x + (size_t)(b * CN) * (HN * WN);
  const int col = 2 * wo;
  float acc[KK];
#pragma unroll
  for (int m = 0; m < KK; ++m) acc[m] = 0.f;
  float2 xbuf[2][3];
  auto load_ch = [&](int ci, float2* dst) {
    const float* xc = xb + (size_t)(c_base + ci) * (HN * WN);
    dst[0] = (ho > 0) ? *(const float2*)(xc + (2 * ho - 1) * WN + col)
                      : make_float2(0.f, 0.f);
    dst[1] = *(const float2*)(xc + (2 * ho) * WN + col);
    dst[2] = *(const float2*)(xc + (2 * ho + 1) * WN + col);
  };
  load_ch(0, xbuf[0]);
  load_ch(1, xbuf[1]);
  const float wok = (wo > 0) ? 1.f : 0.f;
  for (int ci = 0; ci < 16; ++ci) {
    float2 r0 = xbuf[ci & 1][0], r1 = xbuf[ci & 1][1], r2 = xbuf[ci & 1][2];
    if (ci + 2 < 16) load_ch(ci + 2, xbuf[ci & 1]);
    float xv[9];
    xv[0] = wok * __shfl_up(r0.y, 1, 64); xv[1] = r0.x; xv[2] = r0.y;
    xv[3] = wok * __shfl_up(r1.y, 1, 64); xv[4] = r1.x; xv[5] = r1.y;
    xv[6] = wok * __shfl_up(r2.y, 1, 64); xv[7] = r2.x; xv[8] = r2.y;
    const float* __restrict__ wrow = w2c + (size_t)(c_base + ci) * FB_WSTRIDE;
#pragma unroll
    for (int m = 0; m < KK; ++m) {
      float a = acc[m];
#pragma unroll
      for (int t = 0; t < 9; ++t) a += wrow[m * 9 + t] * xv[t];
      acc[m] = a;
    }
  }
  float2 g[2][5];
  auto load_g = [&](int ci, float2* dst) {
    const float* xc = xb + (size_t)(c_base + ci) * (HN * WN);
#pragma unroll
    for (int i = 0; i < 5; ++i) {
      int r = 2 * ho - 2 + i;
      dst[i] = (r >= 0 && r < HN) ? *(const float2*)(xc + r * WN + col)
                                  : make_float2(0.f, 0.f);
    }
  };
  load_g(0, g[0]);
  load_g(1, g[1]);
  if (wv >= 8) {
#pragma unroll
    for (int m = 0; m < KK; ++m) red[((wv - 8) * KK + m) * 64 + wo] = acc[m];
  }
  __syncthreads();
  if (wv < 8) {
#pragma unroll
    for (int m = 0; m < KK; ++m) red[(wv * KK + m) * 64 + wo] += acc[m];
  }
  __syncthreads();
  if (wv < 4) {
#pragma unroll
    for (int m = 0; m < KK; ++m)
      red[(wv * KK + m) * 64 + wo] += red[((wv + 4) * KK + m) * 64 + wo];
  }
  __syncthreads();
  if (wv < 2) {
#pragma unroll
    for (int m = 0; m < KK; ++m)
      red[(wv * KK + m) * 64 + wo] += red[((wv + 2) * KK + m) * 64 + wo];
  }
  __syncthreads();
  if (tid < 64) {
    const float vr0 = (ho > 0) ? 1.f : 0.f;
    const float vq0 = (wo > 0) ? 1.f : 0.f;
    float logit[KK];
    float mx = -1e30f;
#pragma unroll
    for (int m = 0; m < KK; ++m) {
      const float* t9 = tb + m * 9;
      float l = b2[m]
              + vr0 * (vq0 * t9[0] + t9[1] + t9[2])
              +       (vq0 * t9[3] + t9[4] + t9[5])
              +       (vq0 * t9[6] + t9[7] + t9[8]);
      l += red[(0 * KK + m) * 64 + wo] + red[(1 * KK + m) * 64 + wo];
      logit[m] = l;
      mx = fmaxf(mx, l);
    }
    float s = 0.f;
#pragma unroll
    for (int m = 0; m < KK; ++m) {
      float e = __expf(logit[m] - mx);
      logit[m] = e;
      s += e;
    }
    float inv = 1.f / s;
#pragma unroll
    for (int m = 0; m < KK; ++m) sm[m * 64 + wo] = logit[m] * inv;
  }
  __syncthreads();
  float smr[KK];
#pragma unroll
  for (int m = 0; m < KK; ++m) smr[m] = sm[m * 64 + wo];
  const float w63 = (wo < 63) ? 1.f : 0.f;
  for (int ci = 0; ci < 16; ++ci) {
    float2 v[5];
#pragma unroll
    for (int i = 0; i < 5; ++i) v[i] = g[ci & 1][i];
    if (ci + 2 < 16) load_g(ci + 2, g[ci & 1]);
    float acc2 = 0.f;
#pragma unroll
    for (int i = 0; i < 5; ++i) {
      float lx = wok * __shfl_up(v[i].x, 1, 64);
      float ly = wok * __shfl_up(v[i].y, 1, 64);
      float rx = w63 * __shfl_down(v[i].x, 1, 64);
      acc2 += lx * smr[i * 5 + 0] + ly * smr[i * 5 + 1]
            + v[i].x * smr[i * 5 + 2] + v[i].y * smr[i * 5 + 3]
            + rx * smr[i * 5 + 4];
    }
    out[(((size_t)(b * CN + c_base + ci)) * HO + ho) * WO + wo] = acc2;
  }
}

// ---------------------------------------------------------------------------
extern "C" void kernel_launch(void* const* d_in, const int* in_sizes, int n_in,
                              void* d_out, int out_size, void* d_ws, size_t ws_size,
                              hipStream_t stream) {
  const float* x  = (const float*)d_in[0];
  const float* w1 = (const float*)d_in[1];
  const float* b1 = (const float*)d_in[2];
  const float* w2 = (const float*)d_in[3];
  const float* b2 = (const float*)d_in[4];
  float* out = (float*)d_out;
  float* ws  = (float*)d_ws;

  if (ws_size >= WS_NEED) {
    hipLaunchKernelGGL(compose_frags, dim3(68), dim3(64), 0, stream,
                       w1, w2, ws);
    hipLaunchKernelGGL(compress_kernel, dim3(HN, BN), dim3(512), 0, stream,
                       x, b1, ws);
    hipLaunchKernelGGL(mask_softmax, dim3(HO, BN), dim3(256), 0, stream,
                       b2, ws);
    hipLaunchKernelGGL(gather_kernel, dim3(1024), dim3(256), 0, stream,
                       ws, x, out);
  } else {
    hipLaunchKernelGGL(compose_w_fb, dim3(225), dim3(256), 0, stream,
                       w1, b1, w2, ws);
    hipLaunchKernelGGL(fused_fb, dim3(HO, BN), dim3(1024), 0, stream,
                       x, b2, ws, out);
  }
}

// Round 7
// 139.101 us; speedup vs baseline: 1.0861x; 1.0006x over previous
//
#include <hip/hip_runtime.h>
#include <math.h>

// Problem constants
#define BN   4
#define CN   256
#define HN   128
#define WN   128
#define COMP 64
#define KK   25      // K*K taps
#define HO   64
#define WO   64

// ---------------- workspace layout (float offsets) ----------------
// w2A  : 9 t x 4 kidx x 64 lane x 8 bf16    = 18432 u16 = 9216 float slots
// mask : BN*HO*KK*64 fp32                    = 409600 floats
// comp : BN*HN*WN*COMP bf16                  = 4194304 u16 = 2097152 slots
#define W2A_OFF  8192
#define MASK_OFF 17408
#define COMP_OFF 427008
#define WS_NEED  ((size_t)(COMP_OFF + (size_t)BN * HN * WN * COMP / 2) * 4)

typedef short v8s  __attribute__((ext_vector_type(8)));
typedef float v16f __attribute__((ext_vector_type(16)));

__device__ inline ushort f2bf(float f) {       // fp32 -> bf16 bits, RNE
  unsigned u = __float_as_uint(f);
  return (ushort)((u + 0x7fffu + ((u >> 16) & 1u)) >> 16);
}

// ---------------------------------------------------------------------------
// compress: comp[b][h][px][ch] = bf16( w1 . x + b1 ).  Flattened grid, 517
// blocks x 512 thr:
//   blocks 0..511  : compress (h = bid&127, b = bid>>7). Per-block w1 is
//     staged fp32->bf16 into XOR-swizzled LDS ((ch&7)<<4) and B-frags are
//     ds_read from it -- byte-identical values to the R4-R6 composed w1B
//     (same f2bf on the same w1 elements, same lane mapping), so the MFMA
//     math is unchanged. One barrier; then the proven 8-wave MFMA chain
//     (wave w: px-tile tw=w&3, ch-half nt=w>>2; 16 MFMA, no further syncs).
//   blocks 512..516: compose w2A frags (5 blocks x 8 waves = 40 slots, 36
//     used). w2A is consumed only by the NEXT launch (mask_softmax) ->
//     stream-ordered, no race. This deletes the compose_frags launch.
// D layout: col(ch)=lane&31, row(px)=(reg&3)+8*(reg>>2)+4*(lane>>5).
// ---------------------------------------------------------------------------
__global__ __launch_bounds__(512, 4) void compress_kernel(
    const float* __restrict__ x, const float* __restrict__ b1,
    const float* __restrict__ w1, const float* __restrict__ w2,
    float* __restrict__ ws) {
  const int bid = blockIdx.x;
  const int tid = threadIdx.x;
  const int lane = tid & 63, w = tid >> 6;     // w 0..7

  if (bid >= 512) {
    // ---- w2A compose (R4-proven values, 8-wave remap) ----
    const int g = (bid - 512) * 8 + w;         // 0..39, use <36
    if (g < 36) {
      const int t = g >> 2, kidx = g & 3;
      const int m = lane & 31;
      const int kk0 = kidx * 16 + (lane >> 5) * 8;
      ushort pk[8];
#pragma unroll
      for (int j = 0; j < 8; ++j) {
        float v = (m < KK) ? w2[((size_t)(m * COMP + kk0 + j)) * 9 + t] : 0.f;
        pk[j] = f2bf(v);
      }
      ushort* dst = (ushort*)(ws + W2A_OFF) + ((size_t)((t * 4 + kidx) * 64 + lane)) * 8;
      *(ushort4*)(dst)     = make_ushort4(pk[0], pk[1], pk[2], pk[3]);
      *(ushort4*)(dst + 4) = make_ushort4(pk[4], pk[5], pk[6], pk[7]);
    }
    return;
  }

  const int h = bid & 127, b = bid >> 7;

  // ---- stage w1 (64 ch x 256 c) fp32 -> bf16, XOR-swizzled LDS ----
  __shared__ __attribute__((aligned(16))) char w1s[32768];
#pragma unroll
  for (int i = 0; i < 4; ++i) {
    const int gi = i * 512 + tid;              // 0..2047 granules of 8 bf16
    const int ch = gi >> 5;                    // 0..63
    const int cs = (gi & 31) * 8;              // 0..248
    const float* src = w1 + (size_t)ch * CN + cs;
    const float4 a  = *(const float4*)src;
    const float4 c4 = *(const float4*)(src + 4);
    v8s o;
    o[0] = (short)f2bf(a.x);  o[1] = (short)f2bf(a.y);
    o[2] = (short)f2bf(a.z);  o[3] = (short)f2bf(a.w);
    o[4] = (short)f2bf(c4.x); o[5] = (short)f2bf(c4.y);
    o[6] = (short)f2bf(c4.z); o[7] = (short)f2bf(c4.w);
    const int boff = ((ch * CN + cs) * 2) ^ ((ch & 7) << 4);
    *(v8s*)(w1s + boff) = o;
  }
  __syncthreads();

  // ---- MFMA chain (R6-proven) ----
  const int tw = w & 3, nt = w >> 2;           // px-tile, ch-half
  const int nn = lane & 31, kh = lane >> 5;
  const int px = tw * 32 + nn;
  const int chv = nt * 32 + nn;                // compress output channel
  v16f acc = {};
#pragma unroll 2
  for (int kidx = 0; kidx < 16; ++kidx) {
    const float* xc = x + (((size_t)(b * CN + kidx * 16 + kh * 8)) * HN + h) * WN + px;
    float av[8];
#pragma unroll
    for (int j = 0; j < 8; ++j) av[j] = xc[(size_t)j * (HN * WN)];
    v8s af;
#pragma unroll
    for (int j = 0; j < 8; ++j) af[j] = (short)f2bf(av[j]);
    const int c0 = kidx * 16 + kh * 8;
    const int boff = ((chv * CN + c0) * 2) ^ ((chv & 7) << 4);
    const v8s bf = *(const v8s*)(w1s + boff);
    acc = __builtin_amdgcn_mfma_f32_32x32x16_bf16(af, bf, acc, 0, 0, 0);
  }
  ushort* comp = (ushort*)(ws + COMP_OFF);
  const size_t rowbase = (size_t)(b * HN + h) * WN;
  const float bias = b1[nt * 32 + nn];
#pragma unroll
  for (int rg = 0; rg < 16; ++rg) {
    const int pr = tw * 32 + (rg & 3) + 8 * (rg >> 2) + 4 * kh;
    comp[(rowbase + pr) * COMP + nt * 32 + nn] = f2bf(acc[rg] + bias);
  }
}

// ---------------------------------------------------------------------------
// mask_softmax: grid (HO, BN) x 256 thr (4 waves). (R4-proven, unchanged)
// ---------------------------------------------------------------------------
#define MS_LDS 49152
__global__ __launch_bounds__(256, 4) void mask_softmax(
    const float* __restrict__ b2, float* __restrict__ ws) {
  const int ho = blockIdx.x, b = blockIdx.y;
  const int tid = threadIdx.x;
  const int lane = tid & 63, w = tid >> 6;
  __shared__ __attribute__((aligned(16))) char smem[MS_LDS];
  float* red = (float*)smem;                   // alias after barrier
  const ushort* comp = (const ushort*)(ws + COMP_OFF);

  // ---- stage 3 rows (3*128*8 = 3072 v8s) ----
#pragma unroll
  for (int i = 0; i < 12; ++i) {
    const int flat = i * 256 + tid;            // 0..3071
    const int r = flat >> 10;                  // 0..2
    const int px = (flat >> 3) & 127;
    const int cg = flat & 7;
    const int rr = 2 * ho + r - 1;
    v8s v = {};
    if (rr >= 0)
      v = *(const v8s*)(comp + ((size_t)(b * HN + rr) * WN + px) * COMP + cg * 8);
    const int boff = (((r * 128 + px) * 64 + cg * 8) * 2) ^ (((px >> 1) & 7) << 4);
    *(v8s*)(smem + boff) = v;
  }
  __syncthreads();

  // ---- MFMA ----
  const int nt = w & 1, kh2 = w >> 1;
  const int nn = lane & 31;
  const ushort* w2A = (const ushort*)(ws + W2A_OFF);
  const v8s zero8 = {};
  v16f acc = {};
#pragma unroll
  for (int t = 0; t < 9; ++t) {
    const int dr = t / 3, dc = t % 3;
#pragma unroll
    for (int ki = 0; ki < 2; ++ki) {
      const int kidx = kh2 * 2 + ki;
      const v8s af = *(const v8s*)(w2A + ((size_t)((t * 4 + kidx) * 64 + lane)) * 8);
      const int q = 2 * (nt * 32 + nn) + dc - 1;
      const bool bad = q < 0;                  // only nt==0, nn==0, dc==0
      const int qc = bad ? 0 : q;
      const int boff = (((dr * 128 + qc) * 64 + kidx * 16 + (lane >> 5) * 8) * 2)
                       ^ (((qc >> 1) & 7) << 4);
      v8s bf = *(const v8s*)(smem + boff);
      if (dc == 0 && bad) bf = zero8;
      acc = __builtin_amdgcn_mfma_f32_32x32x16_bf16(af, bf, acc, 0, 0, 0);
    }
  }
  __syncthreads();                             // stage reads done; red aliases

  // ---- reduce over kh2 ----
  if (kh2 == 1) {
#pragma unroll
    for (int rg = 0; rg < 16; ++rg) {
      const int m = (rg & 3) + 8 * (rg >> 2) + 4 * (lane >> 5);
      if (m < KK) red[(nt * KK + m) * 32 + nn] = acc[rg];
    }
  }
  __syncthreads();
  if (kh2 == 0) {
#pragma unroll
    for (int rg = 0; rg < 16; ++rg) {
      const int m = (rg & 3) + 8 * (rg >> 2) + 4 * (lane >> 5);
      if (m < KK) red[(nt * KK + m) * 32 + nn] += acc[rg];
    }
  }
  __syncthreads();

  // ---- softmax (64 threads, one per wo) ----
  if (tid < 64) {
    const int wo = tid;
    const int tnt = wo >> 5, tc = wo & 31;
    float logit[KK];
    float mx = -1e30f;
#pragma unroll
    for (int m = 0; m < KK; ++m) {
      float l = b2[m] + red[(tnt * KK + m) * 32 + tc];
      logit[m] = l;
      mx = fmaxf(mx, l);
    }
    float ssum = 0.f;
#pragma unroll
    for (int m = 0; m < KK; ++m) {
      float e = __expf(logit[m] - mx);
      logit[m] = e;
      ssum += e;
    }
    const float inv = 1.f / ssum;
    float* mdst = ws + MASK_OFF + (size_t)(b * HO + ho) * KK * 64;
#pragma unroll
    for (int m = 0; m < KK; ++m) mdst[m * 64 + wo] = logit[m] * inv;
  }
}

// ---------------------------------------------------------------------------
// gather: 1024 blocks x 256 thr (4 waves). (R6-proven, unchanged)
// 4-deep prefetch ring, statically indexed; XCD-bijective block swizzle.
// ---------------------------------------------------------------------------
__global__ __launch_bounds__(256, 4) void gather_kernel(
    const float* __restrict__ ws, const float* __restrict__ x,
    float* __restrict__ out) {
  const int bid0 = blockIdx.x;
  const int bid = (bid0 & 7) * 128 + (bid0 >> 3);   // bijective (1024 = 8*128)
  const int ho = bid & 63;
  const int cq = (bid >> 6) & 3;
  const int b = bid >> 8;
  const int tid = threadIdx.x;
  const int lane = tid & 63, wv = tid >> 6;

  __shared__ float sml[KK * 64];               // 6400 B

  const float* __restrict__ xb = x + (size_t)(b * CN) * (HN * WN);
  const int wo = lane;
  const int c_base = __builtin_amdgcn_readfirstlane(cq * 64 + wv * 16);
  const int col = 2 * wo;
  float2 g[4][5];
  auto load_g = [&](int ci, float2* dst) {
    const float* xc = xb + (size_t)(c_base + ci) * (HN * WN);
#pragma unroll
    for (int i = 0; i < 5; ++i) {
      int r = 2 * ho - 2 + i;
      dst[i] = (r >= 0 && r < HN) ? *(const float2*)(xc + r * WN + col)
                                  : make_float2(0.f, 0.f);
    }
  };
  load_g(0, g[0]);
  load_g(1, g[1]);
  load_g(2, g[2]);
  load_g(3, g[3]);

  const float* msrc = ws + MASK_OFF + (size_t)(b * HO + ho) * KK * 64;
  for (int i = tid; i < KK * 64; i += 256) sml[i] = msrc[i];
  __syncthreads();

  float smr[KK];
#pragma unroll
  for (int m = 0; m < KK; ++m) smr[m] = sml[m * 64 + wo];

  const float wok = (wo > 0) ? 1.f : 0.f;
  const float w63 = (wo < 63) ? 1.f : 0.f;
#pragma unroll
  for (int ci = 0; ci < 16; ++ci) {
    float2 v[5];
#pragma unroll
    for (int i = 0; i < 5; ++i) v[i] = g[ci & 3][i];
    if (ci + 4 < 16) load_g(ci + 4, g[ci & 3]);

    float acc2 = 0.f;
#pragma unroll
    for (int i = 0; i < 5; ++i) {
      float lx = wok * __shfl_up(v[i].x, 1, 64);    // col 2wo-2
      float ly = wok * __shfl_up(v[i].y, 1, 64);    // col 2wo-1
      float rx = w63 * __shfl_down(v[i].x, 1, 64);  // col 2wo+2
      acc2 += lx * smr[i * 5 + 0] + ly * smr[i * 5 + 1]
            + v[i].x * smr[i * 5 + 2] + v[i].y * smr[i * 5 + 3]
            + rx * smr[i * 5 + 4];
    }
    out[(((size_t)(b * CN + c_base + ci)) * HO + ho) * WO + wo] = acc2;
  }
}

// ============================ FALLBACK PATH ================================
// Round-2 proven kernels (used only if ws_size < WS_NEED).
#define FB_WSTRIDE 240
#define FB_TB_OFF  (256 * FB_WSTRIDE)

__global__ __launch_bounds__(256) void compose_w_fb(
    const float* __restrict__ w1, const float* __restrict__ b1,
    const float* __restrict__ w2, float* __restrict__ ws) {
  int mt = blockIdx.x, c = threadIdx.x;
  float acc = 0.f;
#pragma unroll 8
  for (int k = 0; k < COMP; ++k)
    acc += w2[(size_t)(mt / 9 * COMP + k) * 9 + (mt % 9)] * w1[k * CN + c];
  ws[c * FB_WSTRIDE + mt] = acc;
  if (mt < FB_WSTRIDE - 225) ws[c * FB_WSTRIDE + 225 + mt] = 0.f;
  if (c == 0) {
    float tbv = 0.f;
    for (int k = 0; k < COMP; ++k)
      tbv += w2[(size_t)(mt / 9 * COMP + k) * 9 + (mt % 9)] * b1[k];
    ws[FB_TB_OFF + mt] = tbv;
  }
}

__global__ __launch_bounds__(1024, 4) void fused_fb(
    const float* __restrict__ x, const float* __restrict__ b2,
    const float* __restrict__ ws, float* __restrict__ out) {
  const int ho = blockIdx.x, b = blockIdx.y, tid = threadIdx.x;
  const int wo = tid & 63, wv = tid >> 6;
  const int c_base = __builtin_amdgcn_readfirstlane(wv * 16);
  const float* __restrict__ w2c = ws;
  const float* __restrict__ tb  = ws + FB_TB_OFF;
  __shared__ float red[8 * KK * 64];
  __shared__ float sm[KK * 64];
  const float* __restrict__ xb = x + (size_t)(b * CN) * (HN * WN);
  const int col = 2 * wo;
  float acc[KK];
#pragma unroll
  for (int m = 0; m < KK; ++m) acc[m] = 0.f;
  float2 xbuf[2][3];
  auto load_ch = [&](int ci, float2* dst) {
    const float* xc = xb + (size_t)(c_base + ci) * (HN * WN);
    dst[0] = (ho > 0) ? *(const float2*)(xc + (2 * ho - 1) * WN + col)
                      : make_float2(0.f, 0.f);
    dst[1] = *(const float2*)(xc + (2 * ho) * WN + col);
    dst[2] = *(const float2*)(xc + (2 * ho + 1) * WN + col);
  };
  load_ch(0, xbuf[0]);
  load_ch(1, xbuf[1]);
  const float wok = (wo > 0) ? 1.f : 0.f;
  for (int ci = 0; ci < 16; ++ci) {
    float2 r0 = xbuf[ci & 1][0], r1 = xbuf[ci & 1][1], r2 = xbuf[ci & 1][2];
    if (ci + 2 < 16) load_ch(ci + 2, xbuf[ci & 1]);
    float xv[9];
    xv[0] = wok * __shfl_up(r0.y, 1, 64); xv[1] = r0.x; xv[2] = r0.y;
    xv[3] = wok * __shfl_up(r1.y, 1, 64); xv[4] = r1.x; xv[5] = r1.y;
    xv[6] = wok * __shfl_up(r2.y, 1, 64); xv[7] = r2.x; xv[8] = r2.y;
    const float* __restrict__ wrow = w2c + (size_t)(c_base + ci) * FB_WSTRIDE;
#pragma unroll
    for (int m = 0; m < KK; ++m) {
      float a = acc[m];
#pragma unroll
      for (int t = 0; t < 9; ++t) a += wrow[m * 9 + t] * xv[t];
      acc[m] = a;
    }
  }
  float2 g[2][5];
  auto load_g = [&](int ci, float2* dst) {
    const float* xc = xb + (size_t)(c_base + ci) * (HN * WN);
#pragma unroll
    for (int i = 0; i < 5; ++i) {
      int r = 2 * ho - 2 + i;
      dst[i] = (r >= 0 && r < HN) ? *(const float2*)(xc + r * WN + col)
                                  : make_float2(0.f, 0.f);
    }
  };
  load_g(0, g[0]);
  load_g(1, g[1]);
  if (wv >= 8) {
#pragma unroll
    for (int m = 0; m < KK; ++m) red[((wv - 8) * KK + m) * 64 + wo] = acc[m];
  }
  __syncthreads();
  if (wv < 8) {
#pragma unroll
    for (int m = 0; m < KK; ++m) red[(wv * KK + m) * 64 + wo] += acc[m];
  }
  __syncthreads();
  if (wv < 4) {
#pragma unroll
    for (int m = 0; m < KK; ++m)
      red[(wv * KK + m) * 64 + wo] += red[((wv + 4) * KK + m) * 64 + wo];
  }
  __syncthreads();
  if (wv < 2) {
#pragma unroll
    for (int m = 0; m < KK; ++m)
      red[(wv * KK + m) * 64 + wo] += red[((wv + 2) * KK + m) * 64 + wo];
  }
  __syncthreads();
  if (tid < 64) {
    const float vr0 = (ho > 0) ? 1.f : 0.f;
    const float vq0 = (wo > 0) ? 1.f : 0.f;
    float logit[KK];
    float mx = -1e30f;
#pragma unroll
    for (int m = 0; m < KK; ++m) {
      const float* t9 = tb + m * 9;
      float l = b2[m]
              + vr0 * (vq0 * t9[0] + t9[1] + t9[2])
              +       (vq0 * t9[3] + t9[4] + t9[5])
              +       (vq0 * t9[6] + t9[7] + t9[8]);
      l += red[(0 * KK + m) * 64 + wo] + red[(1 * KK + m) * 64 + wo];
      logit[m] = l;
      mx = fmaxf(mx, l);
    }
    float s = 0.f;
#pragma unroll
    for (int m = 0; m < KK; ++m) {
      float e = __expf(logit[m] - mx);
      logit[m] = e;
      s += e;
    }
    float inv = 1.f / s;
#pragma unroll
    for (int m = 0; m < KK; ++m) sm[m * 64 + wo] = logit[m] * inv;
  }
  __syncthreads();
  float smr[KK];
#pragma unroll
  for (int m = 0; m < KK; ++m) smr[m] = sm[m * 64 + wo];
  const float w63 = (wo < 63) ? 1.f : 0.f;
  for (int ci = 0; ci < 16; ++ci) {
    float2 v[5];
#pragma unroll
    for (int i = 0; i < 5; ++i) v[i] = g[ci & 1][i];
    if (ci + 2 < 16) load_g(ci + 2, g[ci & 1]);
    float acc2 = 0.f;
#pragma unroll
    for (int i = 0; i < 5; ++i) {
      float lx = wok * __shfl_up(v[i].x, 1, 64);
      float ly = wok * __shfl_up(v[i].y, 1, 64);
      float rx = w63 * __shfl_down(v[i].x, 1, 64);
      acc2 += lx * smr[i * 5 + 0] + ly * smr[i * 5 + 1]
            + v[i].x * smr[i * 5 + 2] + v[i].y * smr[i * 5 + 3]
            + rx * smr[i * 5 + 4];
    }
    out[(((size_t)(b * CN + c_base + ci)) * HO + ho) * WO + wo] = acc2;
  }
}

// ---------------------------------------------------------------------------
extern "C" void kernel_launch(void* const* d_in, const int* in_sizes, int n_in,
                              void* d_out, int out_size, void* d_ws, size_t ws_size,
                              hipStream_t stream) {
  const float* x  = (const float*)d_in[0];
  const float* w1 = (const float*)d_in[1];
  const float* b1 = (const float*)d_in[2];
  const float* w2 = (const float*)d_in[3];
  const float* b2 = (const float*)d_in[4];
  float* out = (float*)d_out;
  float* ws  = (float*)d_ws;

  if (ws_size >= WS_NEED) {
    hipLaunchKernelGGL(compress_kernel, dim3(517), dim3(512), 0, stream,
                       x, b1, w1, w2, ws);
    hipLaunchKernelGGL(mask_softmax, dim3(HO, BN), dim3(256), 0, stream,
                       b2, ws);
    hipLaunchKernelGGL(gather_kernel, dim3(1024), dim3(256), 0, stream,
                       ws, x, out);
  } else {
    hipLaunchKernelGGL(compose_w_fb, dim3(225), dim3(256), 0, stream,
                       w1, b1, w2, ws);
    hipLaunchKernelGGL(fused_fb, dim3(HO, BN), dim3(1024), 0, stream,
                       x, b2, ws, out);
  }
}